// Round 1
// baseline (191.666 us; speedup 1.0000x reference)
//
#include <hip/hip_runtime.h>
#include <cstddef>

// InfoNCE loss, B=8192, D=128.
// Pipeline: prep (normalize + bf16 cast + label/conf signs + self-dot)
//        -> sim  (bf16 MFMA E·E^T tiles, exp + masked row-sum accumulate, atomics)
//        -> fin  (per-row loss, mean over valid rows)

#define DDIM 128
#define TEMP_SCALE 14.4269504088896340736f  // (1/0.1) * log2(e), folded into A-side

typedef short s8bf __attribute__((ext_vector_type(8)));   // 8 bf16 values as shorts (4 VGPRs)
typedef float f32x4 __attribute__((ext_vector_type(4)));

__device__ __forceinline__ unsigned short f2bf(float f) {
    // round-to-nearest-even fp32 -> bf16 (no NaN/Inf in this data)
    unsigned int u = __float_as_uint(f);
    u += 0x7fffu + ((u >> 16) & 1u);
    return (unsigned short)(u >> 16);
}
__device__ __forceinline__ float bf2f(unsigned short h) {
    return __uint_as_float(((unsigned int)h) << 16);
}

// ---------------- prep: one wave per row ----------------
__global__ __launch_bounds__(256) void prep_kernel(
    const float* __restrict__ emb, const int* __restrict__ labels,
    const float* __restrict__ conf,
    short* __restrict__ Ea,   // bf16(SCALE * e)  (A-side, pre-scaled)
    short* __restrict__ Eb,   // bf16(e)          (B-side)
    float2* __restrict__ lh,  // (label ±1, sign(conf))
    float* __restrict__ sd,   // self-dot in bf16 precision (scaled): diag of sim*SCALE
    float* __restrict__ pos_sum, float* __restrict__ tot_sum, int B)
{
    int wave = threadIdx.x >> 6;
    int lane = threadIdx.x & 63;
    int row  = blockIdx.x * 4 + wave;
    if (row >= B) return;

    float2 x = ((const float2*)(emb + (size_t)row * DDIM))[lane];
    float ss = x.x * x.x + x.y * x.y;
    #pragma unroll
    for (int m = 32; m; m >>= 1) ss += __shfl_xor(ss, m);
    float inv = 1.0f / fmaxf(sqrtf(ss), 1e-12f);

    float e0 = x.x * inv, e1 = x.y * inv;
    unsigned short ea0 = f2bf(TEMP_SCALE * e0), ea1 = f2bf(TEMP_SCALE * e1);
    unsigned short eb0 = f2bf(e0),              eb1 = f2bf(e1);
    *(ushort2*)(Ea + (size_t)row * DDIM + lane * 2) = make_ushort2(ea0, ea1);
    *(ushort2*)(Eb + (size_t)row * DDIM + lane * 2) = make_ushort2(eb0, eb1);

    // self-dot with the SAME rounded bf16 values the MFMA will consume
    float p = bf2f(ea0) * bf2f(eb0) + bf2f(ea1) * bf2f(eb1);
    #pragma unroll
    for (int m = 32; m; m >>= 1) p += __shfl_xor(p, m);

    if (lane == 0) {
        sd[row] = p;
        float l = labels[row] ? 1.0f : -1.0f;       // {0,1} -> {-1,+1}
        float c = conf[row];
        float h = (c > 0.0f) ? 1.0f : ((c < 0.0f) ? -1.0f : 0.0f);
        lh[row] = make_float2(l, h);
        pos_sum[row] = 0.0f;                        // ws is poisoned each call
        tot_sum[row] = 0.0f;
    }
}

// ---------------- sim: MFMA + masked exp row-sums ----------------
// Block = 256 thr = 4 waves. Each wave owns 16 rows; block = 64-row stripe.
// Grid.y splits the 8192 columns into chunks; accumulators live in registers
// across the whole column chunk, one atomicAdd per row per block at the end.
__global__ __launch_bounds__(256) void sim_kernel(
    const short* __restrict__ Ea, const short* __restrict__ Eb,
    const float2* __restrict__ lh,
    float* __restrict__ pos_sum, float* __restrict__ tot_sum,
    int B, int colTilesPerBlock)
{
    int lane = threadIdx.x & 63;
    int wave = threadIdx.x >> 6;
    int l16  = lane & 15;
    int quad = lane >> 4;
    int rowBase = blockIdx.x * 64 + wave * 16;
    int colBase = blockIdx.y * colTilesPerBlock * 16;

    // A fragments: A[m=l16][k=quad*8+j], contiguous 8 bf16 = one b128. Loop-invariant.
    s8bf a[4];
    #pragma unroll
    for (int kc = 0; kc < 4; ++kc)
        a[kc] = *(const s8bf*)(Ea + (size_t)(rowBase + l16) * DDIM + kc * 32 + quad * 8);

    // C/D layout (verified): col = lane&15, row = quad*4 + reg
    float li[4], hi[4];
    #pragma unroll
    for (int r = 0; r < 4; ++r) {
        float2 v = lh[rowBase + quad * 4 + r];
        li[r] = v.x; hi[r] = v.y;
    }

    float pos[4] = {0, 0, 0, 0}, tot[4] = {0, 0, 0, 0};

    for (int t = 0; t < colTilesPerBlock; ++t) {
        int col = colBase + t * 16 + l16;
        // B fragments: B[k][n=l16] = Eb[col][k] -> identical contiguous row load
        s8bf b[4];
        #pragma unroll
        for (int kc = 0; kc < 4; ++kc)
            b[kc] = *(const s8bf*)(Eb + (size_t)col * DDIM + kc * 32 + quad * 8);

        f32x4 acc = {0.f, 0.f, 0.f, 0.f};
        #pragma unroll
        for (int kc = 0; kc < 4; ++kc)
            acc = __builtin_amdgcn_mfma_f32_16x16x32_bf16(a[kc], b[kc], acc, 0, 0, 0);

        float2 lhj = lh[col];
        #pragma unroll
        for (int r = 0; r < 4; ++r) {
            // conf mask folded into exp argument: exp2(x - 1e30) == 0
            float bias = (hi[r] * lhj.y > 0.0f) ? 0.0f : -1e30f;
            float ps   = (li[r] * lhj.x > 0.0f) ? 1.0f : 0.0f;
            float ex = __builtin_amdgcn_exp2f(acc[r] + bias);
            pos[r] = fmaf(ps, ex, pos[r]);   // includes diagonal; subtracted in fin
            tot[r] += ex;                    // neg = tot - pos later (diag cancels)
        }
    }

    // reduce across the 16 lanes sharing this quad (same rows, different cols)
    #pragma unroll
    for (int r = 0; r < 4; ++r) {
        float p = pos[r], s = tot[r];
        #pragma unroll
        for (int m = 1; m < 16; m <<= 1) {
            p += __shfl_xor(p, m);
            s += __shfl_xor(s, m);
        }
        if (l16 == 0) {
            atomicAdd(&pos_sum[rowBase + quad * 4 + r], p);
            atomicAdd(&tot_sum[rowBase + quad * 4 + r], s);
        }
    }
}

// ---------------- fin: per-row loss, mean over valid ----------------
__global__ __launch_bounds__(1024) void fin_kernel(
    const float* __restrict__ pos_sum, const float* __restrict__ tot_sum,
    const float* __restrict__ sd, const float2* __restrict__ lh,
    float* __restrict__ out, int B)
{
    __shared__ float ssum[16], scnt[16];
    float sum = 0.0f, cnt = 0.0f;
    for (int i = threadIdx.x; i < B; i += 1024) {
        float posr = pos_sum[i];
        float neg  = tot_sum[i] - posr;   // diagonal cancels here
        float diag = (lh[i].y != 0.0f) ? __builtin_amdgcn_exp2f(sd[i]) : 0.0f;
        float pos  = posr - diag;
        if (pos > 0.0f && neg > 0.0f) {
            sum += logf((pos + neg + 1e-8f) / pos);   // = -log(pos/(pos+neg+eps))
            cnt += 1.0f;
        }
    }
    #pragma unroll
    for (int m = 32; m; m >>= 1) {
        sum += __shfl_xor(sum, m);
        cnt += __shfl_xor(cnt, m);
    }
    int wave = threadIdx.x >> 6, lane = threadIdx.x & 63;
    if (lane == 0) { ssum[wave] = sum; scnt[wave] = cnt; }
    __syncthreads();
    if (threadIdx.x == 0) {
        float S = 0.0f, C = 0.0f;
        #pragma unroll
        for (int w = 0; w < 16; ++w) { S += ssum[w]; C += scnt[w]; }
        out[0] = (C > 0.0f) ? S / fmaxf(C, 1.0f) : 0.0f;
    }
}

extern "C" void kernel_launch(void* const* d_in, const int* in_sizes, int n_in,
                              void* d_out, int out_size, void* d_ws, size_t ws_size,
                              hipStream_t stream) {
    const float* emb    = (const float*)d_in[0];
    const int*   labels = (const int*)d_in[1];
    const float* conf   = (const float*)d_in[2];
    float* out = (float*)d_out;
    int B = in_sizes[1];   // 8192

    char* ws = (char*)d_ws;
    size_t off = 0;
    short*  Ea  = (short*)(ws + off);  off += (size_t)B * DDIM * 2;
    short*  Eb  = (short*)(ws + off);  off += (size_t)B * DDIM * 2;
    float2* lh  = (float2*)(ws + off); off += (size_t)B * 8;
    float*  sd  = (float*)(ws + off);  off += (size_t)B * 4;
    float*  pos = (float*)(ws + off);  off += (size_t)B * 4;
    float*  tot = (float*)(ws + off);  off += (size_t)B * 4;

    prep_kernel<<<B / 4, 256, 0, stream>>>(emb, labels, conf, Ea, Eb, lh, sd, pos, tot, B);

    int stripes = B / 64;            // 128
    int chunks  = 8;                 // 1024 blocks -> 4 blocks/CU, 16 waves/CU
    int colTilesPerBlock = B / 16 / chunks;  // 64
    sim_kernel<<<dim3(stripes, chunks), 256, 0, stream>>>(Ea, Eb, lh, pos, tot, B, colTilesPerBlock);

    fin_kernel<<<1, 1024, 0, stream>>>(pos, tot, sd, lh, out, B);
}

// Round 2
// 101.388 us; speedup vs baseline: 1.8904x; 1.8904x over previous
//
#include <hip/hip_runtime.h>
#include <cstddef>

// InfoNCE loss, B=8192, D=128.
// prep: normalize + bf16 cast + label/conf signs + self-dot
// sim:  LDS-staged bf16 MFMA E·E^T, exp + masked row-sums (tot/diff trick)
// fin:  per-row loss, mean over valid rows

#define DDIM 128
#define TEMP_SCALE 14.4269504088896340736f  // (1/0.1) * log2(e), folded into A-side

typedef short s8bf __attribute__((ext_vector_type(8)));   // 8 bf16 (4 VGPRs)
typedef float f32x4 __attribute__((ext_vector_type(4)));

__device__ __forceinline__ unsigned short f2bf(float f) {
    unsigned int u = __float_as_uint(f);
    u += 0x7fffu + ((u >> 16) & 1u);
    return (unsigned short)(u >> 16);
}
__device__ __forceinline__ float bf2f(unsigned short h) {
    return __uint_as_float(((unsigned int)h) << 16);
}

// ---------------- prep: one wave per row ----------------
__global__ __launch_bounds__(256) void prep_kernel(
    const float* __restrict__ emb, const int* __restrict__ labels,
    const float* __restrict__ conf,
    short* __restrict__ Ea,   // bf16(SCALE * e)  (A-side, pre-scaled)
    short* __restrict__ Eb,   // bf16(e)          (B-side)
    float2* __restrict__ lh,  // (label ±1, sign(conf))
    float* __restrict__ sd,   // scaled self-dot (bf16-rounded), diag of sim*SCALE
    float* __restrict__ pos_sum, float* __restrict__ tot_sum, int B)
{
    int wave = threadIdx.x >> 6;
    int lane = threadIdx.x & 63;
    int row  = blockIdx.x * 4 + wave;
    if (row >= B) return;

    float2 x = ((const float2*)(emb + (size_t)row * DDIM))[lane];
    float ss = x.x * x.x + x.y * x.y;
    #pragma unroll
    for (int m = 32; m; m >>= 1) ss += __shfl_xor(ss, m);
    float inv = 1.0f / fmaxf(sqrtf(ss), 1e-12f);

    float e0 = x.x * inv, e1 = x.y * inv;
    unsigned short ea0 = f2bf(TEMP_SCALE * e0), ea1 = f2bf(TEMP_SCALE * e1);
    unsigned short eb0 = f2bf(e0),              eb1 = f2bf(e1);
    *(ushort2*)(Ea + (size_t)row * DDIM + lane * 2) = make_ushort2(ea0, ea1);
    *(ushort2*)(Eb + (size_t)row * DDIM + lane * 2) = make_ushort2(eb0, eb1);

    float p = bf2f(ea0) * bf2f(eb0) + bf2f(ea1) * bf2f(eb1);
    #pragma unroll
    for (int m = 32; m; m >>= 1) p += __shfl_xor(p, m);

    if (lane == 0) {
        sd[row] = p;
        float l = labels[row] ? 1.0f : -1.0f;
        float c = conf[row];
        float h = (c > 0.0f) ? 1.0f : ((c < 0.0f) ? -1.0f : 0.0f);
        lh[row] = make_float2(l, h);
        pos_sum[row] = 0.0f;
        tot_sum[row] = 0.0f;
    }
}

// ---------------- sim ----------------
// Block = 256 thr = 4 waves, owns 128 rows (wave w -> rows w*32..w*32+31, 2 MFMA row-tiles).
// Cols: grid.y chunks; within a chunk, groups of 128 cols staged into padded LDS,
// then 8 col-tiles of 16 per group. tot/diff accumulators persist across all groups.
#define PADS 136   // shorts per LDS row (272 B): bank stride 4 -> 2-way (free)

__global__ __launch_bounds__(256) void sim_kernel(
    const short* __restrict__ Ea, const short* __restrict__ Eb,
    const float2* __restrict__ lh,
    float* __restrict__ pos_sum, float* __restrict__ tot_sum,
    int B, int groupsPerBlock)
{
    __shared__ short tile[128 * PADS];     // 34816 B
    __shared__ float2 lhTile[128];         // 1 KB

    int lane = threadIdx.x & 63;
    int wave = threadIdx.x >> 6;
    int l16  = lane & 15;
    int quad = lane >> 4;
    int rowBase = blockIdx.x * 128 + wave * 32;   // 2 row-tiles: rowBase, rowBase+16

    // A fragments (loop-invariant): A[m=l16][k=quad*8+j], contiguous b128
    s8bf a0[4], a1[4];
    #pragma unroll
    for (int kc = 0; kc < 4; ++kc) {
        a0[kc] = *(const s8bf*)(Ea + (size_t)(rowBase +      l16) * DDIM + kc * 32 + quad * 8);
        a1[kc] = *(const s8bf*)(Ea + (size_t)(rowBase + 16 + l16) * DDIM + kc * 32 + quad * 8);
    }

    // C/D layout: col = lane&15, row = quad*4 + reg
    float li0[4], hi0[4], li1[4], hi1[4];
    #pragma unroll
    for (int r = 0; r < 4; ++r) {
        float2 v0 = lh[rowBase +      quad * 4 + r];
        float2 v1 = lh[rowBase + 16 + quad * 4 + r];
        li0[r] = v0.x; hi0[r] = v0.y;
        li1[r] = v1.x; hi1[r] = v1.y;
    }

    float tot0[4] = {0,0,0,0}, dif0[4] = {0,0,0,0};
    float tot1[4] = {0,0,0,0}, dif1[4] = {0,0,0,0};

    int c0base = blockIdx.y * groupsPerBlock * 128;
    for (int g = 0; g < groupsPerBlock; ++g) {
        int c0 = c0base + g * 128;

        // ---- stage 128 cols (32 KB) into padded LDS, coalesced ----
        const int4* gsrc = (const int4*)(Eb + (size_t)c0 * DDIM);
        #pragma unroll
        for (int i = 0; i < 8; ++i) {
            int chunk = i * 256 + threadIdx.x;       // 0..2047 (16B units)
            int row = chunk >> 4, off = chunk & 15;
            int4 v = gsrc[chunk];
            *(int4*)(tile + row * PADS + off * 8) = v;
        }
        if (threadIdx.x < 128) lhTile[threadIdx.x] = lh[c0 + threadIdx.x];
        __syncthreads();

        // ---- 8 col-tiles of 16 ----
        #pragma unroll 2
        for (int ct = 0; ct < 8; ++ct) {
            s8bf b[4];
            #pragma unroll
            for (int kc = 0; kc < 4; ++kc)
                b[kc] = *(const s8bf*)(tile + (ct * 16 + l16) * PADS + kc * 32 + quad * 8);

            f32x4 acc0 = {0.f,0.f,0.f,0.f}, acc1 = {0.f,0.f,0.f,0.f};
            #pragma unroll
            for (int kc = 0; kc < 4; ++kc) {
                acc0 = __builtin_amdgcn_mfma_f32_16x16x32_bf16(a0[kc], b[kc], acc0, 0, 0, 0);
                acc1 = __builtin_amdgcn_mfma_f32_16x16x32_bf16(a1[kc], b[kc], acc1, 0, 0, 0);
            }

            float2 lhj = lhTile[ct * 16 + l16];
            #pragma unroll
            for (int r = 0; r < 4; ++r) {
                // conf mask -> -inf bias (conf==0 correctly excluded)
                float b0 = (hi0[r] * lhj.y > 0.0f) ? 0.0f : -1e30f;
                float e0 = __builtin_amdgcn_exp2f(acc0[r] + b0);
                tot0[r] += e0;
                dif0[r] = fmaf(li0[r] * lhj.x, e0, dif0[r]);

                float b1 = (hi1[r] * lhj.y > 0.0f) ? 0.0f : -1e30f;
                float e1 = __builtin_amdgcn_exp2f(acc1[r] + b1);
                tot1[r] += e1;
                dif1[r] = fmaf(li1[r] * lhj.x, e1, dif1[r]);
            }
        }
        __syncthreads();
    }

    // ---- reduce over the 16 column-lanes, one atomic pair per row ----
    #pragma unroll
    for (int r = 0; r < 4; ++r) {
        float t0 = tot0[r], d0 = dif0[r], t1 = tot1[r], d1 = dif1[r];
        #pragma unroll
        for (int m = 1; m < 16; m <<= 1) {
            t0 += __shfl_xor(t0, m); d0 += __shfl_xor(d0, m);
            t1 += __shfl_xor(t1, m); d1 += __shfl_xor(d1, m);
        }
        if (l16 == 0) {
            // pos (incl. diagonal) = (tot + dif) / 2 since labels are +-1
            atomicAdd(&pos_sum[rowBase +      quad * 4 + r], 0.5f * (t0 + d0));
            atomicAdd(&tot_sum[rowBase +      quad * 4 + r], t0);
            atomicAdd(&pos_sum[rowBase + 16 + quad * 4 + r], 0.5f * (t1 + d1));
            atomicAdd(&tot_sum[rowBase + 16 + quad * 4 + r], t1);
        }
    }
}

// ---------------- fin ----------------
__global__ __launch_bounds__(1024) void fin_kernel(
    const float* __restrict__ pos_sum, const float* __restrict__ tot_sum,
    const float* __restrict__ sd, const float2* __restrict__ lh,
    float* __restrict__ out, int B)
{
    __shared__ float ssum[16], scnt[16];
    float sum = 0.0f, cnt = 0.0f;
    for (int i = threadIdx.x; i < B; i += 1024) {
        float posr = pos_sum[i];
        float neg  = tot_sum[i] - posr;   // diagonal cancels
        float diag = (lh[i].y != 0.0f) ? __builtin_amdgcn_exp2f(sd[i]) : 0.0f;
        float pos  = posr - diag;
        if (pos > 0.0f && neg > 0.0f) {
            sum += logf((pos + neg + 1e-8f) / pos);
            cnt += 1.0f;
        }
    }
    #pragma unroll
    for (int m = 32; m; m >>= 1) {
        sum += __shfl_xor(sum, m);
        cnt += __shfl_xor(cnt, m);
    }
    int wave = threadIdx.x >> 6, lane = threadIdx.x & 63;
    if (lane == 0) { ssum[wave] = sum; scnt[wave] = cnt; }
    __syncthreads();
    if (threadIdx.x == 0) {
        float S = 0.0f, C = 0.0f;
        #pragma unroll
        for (int w = 0; w < 16; ++w) { S += ssum[w]; C += scnt[w]; }
        out[0] = (C > 0.0f) ? S / fmaxf(C, 1.0f) : 0.0f;
    }
}

extern "C" void kernel_launch(void* const* d_in, const int* in_sizes, int n_in,
                              void* d_out, int out_size, void* d_ws, size_t ws_size,
                              hipStream_t stream) {
    const float* emb    = (const float*)d_in[0];
    const int*   labels = (const int*)d_in[1];
    const float* conf   = (const float*)d_in[2];
    float* out = (float*)d_out;
    int B = in_sizes[1];   // 8192

    char* ws = (char*)d_ws;
    size_t off = 0;
    short*  Ea  = (short*)(ws + off);  off += (size_t)B * DDIM * 2;
    short*  Eb  = (short*)(ws + off);  off += (size_t)B * DDIM * 2;
    float2* lhp = (float2*)(ws + off); off += (size_t)B * 8;
    float*  sd  = (float*)(ws + off);  off += (size_t)B * 4;
    float*  pos = (float*)(ws + off);  off += (size_t)B * 4;
    float*  tot = (float*)(ws + off);  off += (size_t)B * 4;

    prep_kernel<<<B / 4, 256, 0, stream>>>(emb, labels, conf, Ea, Eb, lhp, sd, pos, tot, B);

    int rowBlocks = B / 128;             // 64
    int colChunks = 16;                  // 64*16 = 1024 blocks -> 4 blocks/CU
    int groupsPerBlock = B / 128 / colChunks;  // 4
    sim_kernel<<<dim3(rowBlocks, colChunks), 256, 0, stream>>>(Ea, Eb, lhp, pos, tot, B, groupsPerBlock);

    fin_kernel<<<1, 1024, 0, stream>>>(pos, tot, sd, lhp, out, B);
}